// Round 5
// baseline (57.661 us; speedup 1.0000x reference)
//
#include <hip/hip_runtime.h>

#define L_SEQ 2048
#define HEADS 16
#define DIM   64
#define TILE  32
#define NROWS 34          // delta/E rows 0..33 (rows l0-1 .. l0+32 differences)

typedef __attribute__((ext_vector_type(8))) short bf16x8;
typedef __attribute__((ext_vector_type(4))) float f32x4;

static __device__ __forceinline__ unsigned short f2bf_rtne(float f) {
    unsigned int u = __builtin_bit_cast(unsigned int, f);
    u += 0x7fffu + ((u >> 16) & 1u);
    return (unsigned short)(u >> 16);
}
// pack hi16(a) | hi16(b)<<16 in ONE v_perm_b32 (truncation rounding — error
// budget on the score path is ~1000x the threshold sensitivity)
static __device__ __forceinline__ unsigned int pk2(float a, float b) {
    return __builtin_amdgcn_perm(__builtin_bit_cast(unsigned int, b),
                                 __builtin_bit_cast(unsigned int, a), 0x07060302u);
}
static __device__ __forceinline__ unsigned short f2bf_trunc(float f) {
    return (unsigned short)(__builtin_bit_cast(unsigned int, f) >> 16);
}

// bf16 LDS tiles have 64-ushort (128B) rows -> 16-way conflict unswizzled.
// XOR-swizzle: ushort_col ^ ((row&7)<<3)  == byte ^ ((row&7)<<4).
#define SWZ(row, col) ((row) * 64 + ((col) ^ (((row) & 7) * 8)))

__global__ void prep_w_kernel(const float* __restrict__ W, unsigned short* __restrict__ wbf) {
    int i = blockIdx.x * 256 + threadIdx.x;
    if (i < DIM * DIM) wbf[i] = f2bf_rtne(W[i]);
}

static __device__ __forceinline__ bf16x8 load_bfrag(const unsigned short* wbf,
                                                    const float* W, int n, int k0) {
    if (wbf) return *(const bf16x8*)(wbf + n * 64 + k0);
    const float* wr = W + n * 64 + k0;
    float4 w0 = *(const float4*)wr;
    float4 w1 = *(const float4*)(wr + 4);
    uint4 p;
    p.x = pk2(w0.x, w0.y); p.y = pk2(w0.z, w0.w);
    p.z = pk2(w1.x, w1.y); p.w = pk2(w1.z, w1.w);
    return __builtin_bit_cast(bf16x8, p);
}

// One block = (b, h, 32 consecutive l). 128 threads = 2 waves.
// 16 blocks/CU resident (LDS ~9.3KB, VGPR<=64) -> 16 independent barrier
// scopes per CU to hide latency (stall-bound kernel, see R4 post-mortem).
__global__ __launch_bounds__(128, 8) void betweenness_rope_kernel(
    const float* __restrict__ x, const float* __restrict__ W,
    const unsigned short* __restrict__ wbf, const float* __restrict__ gate,
    float* __restrict__ out)
{
    __shared__ unsigned short dl[NROWS * 64];     // bf16 delta rows, swizzled
    __shared__ unsigned short el[NROWS * 64];     // bf16 E rows, swizzled
    __shared__ float n1s[NROWS];                  // ||D_r||^2
    __shared__ float g1s[33];                     // D_r . D_{r+1}
    __shared__ float2 fl[TILE];                   // per-row {floor(adj_pos), frac}

    const int tid  = threadIdx.x;
    const int lane = tid & 63;
    const int wave = tid >> 6;
    const int la   = lane & 15, lg = lane >> 4;
    const int l0   = blockIdx.x * TILE;
    const int h    = blockIdx.y;
    const int b    = blockIdx.z;
    const int bh_off = (b * L_SEQ * HEADS + h) * DIM;

    // ---- P1: delta rows straight from global (x is L3-resident) ----
    // slot s -> row r = s>>3 (0..33), col block c0 = (s&7)*8
    #pragma unroll
    for (int k = 0; k < 3; ++k) {
        int s = tid + k * 128;
        if (s < NROWS * 8) {
            int r = s >> 3, c0 = (s & 7) * 8;
            int g0 = max(0, min(L_SEQ - 1, l0 - 1 + r));
            int g1 = max(0, min(L_SEQ - 1, l0 + r));
            const float* p0 = x + bh_off + g0 * (HEADS * DIM) + c0;
            const float* p1 = x + bh_off + g1 * (HEADS * DIM) + c0;
            float4 a0 = *(const float4*)p0, a1 = *(const float4*)(p0 + 4);
            float4 b0 = *(const float4*)p1, b1 = *(const float4*)(p1 + 4);
            uint4 o;
            o.x = pk2(b0.x - a0.x, b0.y - a0.y);
            o.y = pk2(b0.z - a0.z, b0.w - a0.w);
            o.z = pk2(b1.x - a1.x, b1.y - a1.y);
            o.w = pk2(b1.z - a1.z, b1.w - a1.w);
            *(uint4*)&dl[SWZ(r, c0)] = o;
        }
    }
    __syncthreads();

    // ---- P2: E = Delta @ W^T via MFMA (12 16x16 tile-jobs over 2 waves) ----
    for (int job = wave; job < 12; job += 2) {
        int mt = job >> 2, nt = job & 3;
        int arow = min(16 * mt + la, NROWS - 1);   // clamp: rows >=34 feed unused D rows
        bf16x8 a0 = *(const bf16x8*)&dl[SWZ(arow, lg * 8)];
        bf16x8 a1 = *(const bf16x8*)&dl[SWZ(arow, lg * 8 + 32)];
        bf16x8 b0 = load_bfrag(wbf, W, 16 * nt + la, lg * 8);
        bf16x8 b1 = load_bfrag(wbf, W, 16 * nt + la, lg * 8 + 32);
        f32x4 acc = {0.f, 0.f, 0.f, 0.f};
        acc = __builtin_amdgcn_mfma_f32_16x16x32_bf16(a0, b0, acc, 0, 0, 0);
        acc = __builtin_amdgcn_mfma_f32_16x16x32_bf16(a1, b1, acc, 0, 0, 0);
        #pragma unroll
        for (int q = 0; q < 4; ++q) {   // D layout: col=lane&15, row=(lane>>4)*4+q
            int R = 16 * mt + lg * 4 + q;
            if (R < NROWS) el[SWZ(R, 16 * nt + la)] = f2bf_trunc(acc[q]);
        }
    }
    __syncthreads();

    // ---- P3: Gram band via MFMA: tiles (0,0),(1,1),(2,2),(0,1),(1,2) ----
    for (int job = wave; job < 5; job += 2) {
        int mt = (job < 3) ? job : job - 3;
        int nt = (job < 3) ? job : job - 2;
        int arow = min(16 * mt + la, NROWS - 1);
        int brow = min(16 * nt + la, NROWS - 1);
        f32x4 g = {0.f, 0.f, 0.f, 0.f};
        #pragma unroll
        for (int kt = 0; kt < 2; ++kt) {
            int cb = lg * 8 + kt * 32;
            bf16x8 a  = *(const bf16x8*)&el[SWZ(arow, cb)];
            bf16x8 bb = *(const bf16x8*)&el[SWZ(brow, cb)];  // B[k][n]=E[n][k]
            g = __builtin_amdgcn_mfma_f32_16x16x32_bf16(a, bb, g, 0, 0, 0);
        }
        #pragma unroll
        for (int q = 0; q < 4; ++q) {
            int R = 16 * mt + lg * 4 + q, C = 16 * nt + la;
            if (C == R && R < NROWS) n1s[R] = g[q];
            if (C == R + 1 && R < 33) g1s[R] = g[q];
        }
    }
    __syncthreads();

    // ---- P4: per-row score -> (flo, frac), computed once (32 threads) ----
    if (tid < TILE) {
        const float gate0 = gate[0];
        int r = tid, l = l0 + r;
        float a1 = n1s[r], b1 = n1s[r + 1], gg = g1s[r];
        float d1a = sqrtf(a1), d1b = sqrtf(b1);
        float dd  = sqrtf(fmaxf(a1 + b1 + 2.f * gg, 0.f));   // ||D_r + D_{r+1}||
        float sc  = fmaxf(1.f - ((d1a + d1b) - dd) / fmaxf(dd, 1e-6f), 0.f);
        float bet = (l >= 1 && l <= L_SEQ - 2) ? sc * (1.f / (L_SEQ - 2)) : 0.f;
        float adjust = gate0 * (bet - 0.5f) * 0.1f;
        float ap  = fminf(fmaxf((float)l + adjust, 0.f), (float)(L_SEQ - 1));
        float flo = floorf(ap);
        fl[r] = make_float2(flo, ap - flo);
    }
    __syncthreads();

    // ---- P5: RoPE epilogue: 2 pairs/lane, float4 load+store, x from cache ----
    {
        const int j2 = lane & 15;       // handles pairs j=2*j2 and j=2*j2+1
        const int rg = lane >> 4;       // row group 0..3
        // fjr = f_j / (2*pi): revolutions per position; f_j = 10000^(-j/32)
        const float fja = __builtin_exp2f(-0.4152410118609203f * (float)(2 * j2))
                        * 0.15915494309189535f;
        const float fjb = __builtin_exp2f(-0.4152410118609203f * (float)(2 * j2 + 1))
                        * 0.15915494309189535f;
        const float cfa = __builtin_amdgcn_cosf(fja), sfa = __builtin_amdgcn_sinf(fja);
        const float cfb = __builtin_amdgcn_cosf(fjb), sfb = __builtin_amdgcn_sinf(fjb);
        const float cfma = cfa - 1.0f, cfmb = cfb - 1.0f;
        #pragma unroll
        for (int it = 0; it < 4; ++it) {
            int r = it * 8 + wave * 4 + rg;       // 0..31
            int l = l0 + r;
            float2 ff = fl[r];
            const float* xp = x + bh_off + l * (HEADS * DIM) + 4 * j2;
            float4 xv = *(const float4*)xp;
            // pair a
            float ta = ff.x * fja;
            float rva = ta - floorf(ta);
            float cla = __builtin_amdgcn_cosf(rva), sla = __builtin_amdgcn_sinf(rva);
            float ua = fmaf(ff.y, cfma, 1.0f);
            float va = ff.y * sfa;
            float cia = fmaf(-sla, va, cla * ua);
            float sia = fmaf(cla, va, sla * ua);
            // pair b
            float tb = ff.x * fjb;
            float rvb = tb - floorf(tb);
            float clb = __builtin_amdgcn_cosf(rvb), slb = __builtin_amdgcn_sinf(rvb);
            float ub = fmaf(ff.y, cfmb, 1.0f);
            float vb = ff.y * sfb;
            float cib = fmaf(-slb, vb, clb * ub);
            float sib = fmaf(clb, vb, slb * ub);
            float4 o;
            o.x = xv.x * cia - xv.y * sia;
            o.y = fmaf(xv.y, cia, xv.x * sia);
            o.z = xv.z * cib - xv.w * sib;
            o.w = fmaf(xv.w, cib, xv.z * sib);
            *(float4*)(out + bh_off + l * (HEADS * DIM) + 4 * j2) = o;
        }
    }
}

extern "C" void kernel_launch(void* const* d_in, const int* in_sizes, int n_in,
                              void* d_out, int out_size, void* d_ws, size_t ws_size,
                              hipStream_t stream) {
    const float* x    = (const float*)d_in[0];
    const float* W    = (const float*)d_in[1];
    const float* gate = (const float*)d_in[3];   // bias cancels in differences
    float* out = (float*)d_out;

    const int B = in_sizes[0] / (L_SEQ * HEADS * DIM);

    unsigned short* wbf = nullptr;
    if (ws_size >= (size_t)(DIM * DIM * sizeof(unsigned short))) {
        wbf = (unsigned short*)d_ws;
        prep_w_kernel<<<16, 256, 0, stream>>>(W, wbf);
    }

    dim3 grid(L_SEQ / TILE, HEADS, B);
    betweenness_rope_kernel<<<grid, 128, 0, stream>>>(x, W, wbf, gate, out);
}